// Round 7
// baseline (136.942 us; speedup 1.0000x reference)
//
#include <hip/hip_runtime.h>
#include <hip/hip_bf16.h>

#define Tlen 8192
#define Dd 256
#define NBc 128

typedef __attribute__((ext_vector_type(4))) float f32x4;
typedef __attribute__((ext_vector_type(16))) float f32x16;
typedef __attribute__((ext_vector_type(8))) short bf16x8;

__device__ __forceinline__ unsigned short f2bf(float f){
  unsigned u = __builtin_bit_cast(unsigned, f);
  u += 0x7fffu + ((u >> 16) & 1u);
  return (unsigned short)(u >> 16);
}
__device__ __forceinline__ f32x4 mfma16(bf16x8 a, bf16x8 b, f32x4 c){
  return __builtin_amdgcn_mfma_f32_16x16x32_bf16(a, b, c, 0, 0, 0);
}
__device__ __forceinline__ f32x16 mfma32(bf16x8 a, bf16x8 b, f32x16 c){
  return __builtin_amdgcn_mfma_f32_32x32x16_bf16(a, b, c, 0, 0, 0);
}
__device__ __forceinline__ unsigned pkbf(float a, float b){
  unsigned r; asm("v_cvt_pk_bf16_f32 %0, %1, %2" : "=v"(r) : "v"(a), "v"(b)); return r;
}
__device__ __forceinline__ void bar(){
  asm volatile("" ::: "memory");
  __builtin_amdgcn_s_barrier();
  asm volatile("" ::: "memory");
}
__device__ __forceinline__ bf16x8 pack8(f32x4 a0, f32x4 a1){
  bf16x8 o;
  o[0]=(short)f2bf(a0[0]); o[1]=(short)f2bf(a0[1]); o[2]=(short)f2bf(a0[2]); o[3]=(short)f2bf(a0[3]);
  o[4]=(short)f2bf(a1[0]); o[5]=(short)f2bf(a1[1]); o[6]=(short)f2bf(a1[2]); o[7]=(short)f2bf(a1[3]);
  return o;
}
#define GLL16(g, l) __builtin_amdgcn_global_load_lds( \
    (const __attribute__((address_space(1))) unsigned int*)(const void*)(g), \
    (__attribute__((address_space(3))) unsigned int*)(void*)(l), 16, 0, 0)

// DPP 16-lane row rotations (lane groups of 16 == DPP rows)
template<int C>
__device__ __forceinline__ int dppi(int x){
  return __builtin_amdgcn_update_dpp(x, x, C, 0xF, 0xF, false);
}
template<int C>
__device__ __forceinline__ float dppf(float x){
  return __builtin_bit_cast(float, dppi<C>(__builtin_bit_cast(int, x)));
}
__device__ __forceinline__ float dpp_sum16(float x){
  x += dppf<0x121>(x); x += dppf<0x122>(x); x += dppf<0x124>(x); x += dppf<0x128>(x);
  return x;
}

// Load A-fragment (row = lane&15) for 16x16x32: 8 consecutive k at (l>>4)*8
__device__ __forceinline__ bf16x8 load_qfrag(const float* qrow, int kc, int g){
  f32x4 v0 = *(const f32x4*)(qrow + kc*32 + g*8);
  f32x4 v1 = *(const f32x4*)(qrow + kc*32 + g*8 + 4);
  return pack8(v0, v1);
}

// ---------------- Prep: means (ck, cvt) + swizzled bf16 K blocks + swizzled bf16 V^T blocks
__global__ __launch_bounds__(256) void k_prep(const float* __restrict__ K, const float* __restrict__ V,
    unsigned short* __restrict__ ck, unsigned short* __restrict__ cvt,
    unsigned short* __restrict__ Vswz, unsigned short* __restrict__ Kswz, int do_k){
  __shared__ unsigned short Lt[64][72];
  int b = blockIdx.x >> 7, blk = blockIdx.x & 127;
  int t = threadIdx.x;
  const float* Kb = K + ((size_t)b*Tlen + (size_t)blk*64)*Dd;
  const float* Vb = V + ((size_t)b*Tlen + (size_t)blk*64)*Dd;
  {
    float sk=0.f, sv=0.f;
    #pragma unroll 8
    for (int i=0;i<64;i++){ sk += Kb[(size_t)i*Dd + t]; sv += Vb[(size_t)i*Dd + t]; }
    ck[((size_t)b*NBc + blk)*Dd + t] = f2bf(sk*(1.f/64.f));
    cvt[((size_t)b*Dd + t)*NBc + blk] = f2bf(sv*(1.f/64.f));
  }
  if (do_k){
    unsigned short* kd = Kswz + ((size_t)(b*NBc + blk))*16384;
    #pragma unroll
    for (int i=0;i<8;i++){
      int id = i*256 + t, r = id>>5, c = id&31;
      f32x4 a0 = *(const f32x4*)(Kb + (size_t)r*Dd + c*8);
      f32x4 a1 = *(const f32x4*)(Kb + (size_t)r*Dd + c*8 + 4);
      *(bf16x8*)(kd + r*256 + ((c ^ (r&7))*8)) = pack8(a0,a1);
    }
  }
  unsigned short* vd = Vswz + ((size_t)(b*NBc + blk))*16384;
  for (int dt=0; dt<4; ++dt){
    __syncthreads();
    #pragma unroll
    for (int it=0; it<4; ++it){
      int idx = it*256 + t, r = idx>>4, c4 = idx&15;
      f32x4 v = *(const f32x4*)(Vb + (size_t)r*Dd + dt*64 + c4*4);
      #pragma unroll
      for (int ii=0;ii<4;ii++) Lt[c4*4+ii][r] = f2bf(v[ii]);
    }
    __syncthreads();
    int dd = t>>2, ch = t&3, d = dt*64 + dd;
    unsigned short tmp[16];
    #pragma unroll
    for (int u=0;u<16;u++) tmp[u] = Lt[dd][ch*16+u];
    *(bf16x8*)(vd + d*64 + (((ch*2  ) ^ (d&7))*8)) = *(bf16x8*)(tmp);
    *(bf16x8*)(vd + d*64 + (((ch*2+1) ^ (d&7))*8)) = *(bf16x8*)(tmp+8);
  }
}

// ---------------- comp + selective branches: DPP float/index argmax top-16 (proven r3 semantics)
__global__ __launch_bounds__(256,1) void k_compsel(const float* __restrict__ Q,
    const unsigned short* __restrict__ ck, const unsigned short* __restrict__ cvt,
    const float* __restrict__ gc, const float* __restrict__ gs, float* __restrict__ out){
  __shared__ unsigned short Pc[64*136];
  int b = blockIdx.x >> 7, tile = blockIdx.x & 127;
  int q0 = tile*64;
  int w = threadIdx.x >> 6, l = threadIdx.x & 63, g = l >> 4, lr = l & 15;

  bf16x8 qa[8];
  const float* qrow = Q + ((size_t)b*Tlen + q0 + w*16 + lr)*Dd;
  #pragma unroll
  for (int kc=0;kc<8;kc++) qa[kc] = load_qfrag(qrow, kc, g);

  f32x4 acc[8];
  #pragma unroll
  for (int nf=0;nf<8;nf++) acc[nf] = f32x4{0.f,0.f,0.f,0.f};
  const unsigned short* ckb = ck + (size_t)b*NBc*Dd;
  #pragma unroll
  for (int nf=0;nf<8;nf++){
    #pragma unroll
    for (int kc=0;kc<8;kc++){
      bf16x8 bb = *(const bf16x8*)(ckb + (size_t)(nf*16+lr)*Dd + kc*32 + g*8);
      acc[nf] = mfma16(qa[kc], bb, acc[nf]);
    }
  }
  #pragma unroll
  for (int nf=0;nf<8;nf++) acc[nf] *= 0.0625f;

  // exp once (scores ~N(0,0.125): no max subtraction needed in fp32)
  bool al[8];
  #pragma unroll
  for (int nf=0;nf<8;nf++) al[nf] = (nf*16+lr) <= tile;
  f32x4 e[8];
  #pragma unroll
  for (int nf=0;nf<8;nf++){
    #pragma unroll
    for (int j=0;j<4;j++) e[nf][j] = __expf(acc[nf][j]);
  }
  // row sums via DPP (zc: all cols; zs: causal-allowed cols)
  f32x4 zc4 = f32x4{0.f,0.f,0.f,0.f}, zs4 = f32x4{0.f,0.f,0.f,0.f};
  #pragma unroll
  for (int nf=0;nf<8;nf++){
    zc4 += e[nf];
    #pragma unroll
    for (int j=0;j<4;j++) zs4[j] += al[nf] ? e[nf][j] : 0.f;
  }
  float rzc[4], rzs[4];
  #pragma unroll
  for (int j=0;j<4;j++){
    rzc[j] = 1.f / dpp_sum16(zc4[j]);
    rzs[j] = 1.f / dpp_sum16(zs4[j]);
  }

  // top-16 extraction: 16 iterations, DPP argmax over the 16-lane row, 4 rows in flight
  f32x4 sm[8];
  #pragma unroll
  for (int nf=0;nf<8;nf++){
    #pragma unroll
    for (int j=0;j<4;j++) sm[nf][j] = al[nf] ? acc[nf][j] : -3e38f;
  }
  unsigned selm[4]={0,0,0,0};
  #pragma unroll 1
  for (int it=0; it<16; ++it){
    float bv[4]; int bi[4];
    #pragma unroll
    for (int j=0;j<4;j++){
      float v = sm[0][j]; int n = lr;
      #pragma unroll
      for (int nf=1;nf<8;nf++){
        bool t = sm[nf][j] > v;
        v = t ? sm[nf][j] : v;
        n = t ? nf*16+lr : n;
      }
      bv[j]=v; bi[j]=n;
    }
    #define DSTEP(CTRL) \
    _Pragma("unroll") \
    for (int j=0;j<4;j++){ \
      float ov = dppf<CTRL>(bv[j]); int oi = dppi<CTRL>(bi[j]); \
      bool t = (ov>bv[j]) || (ov==bv[j] && oi<bi[j]); \
      bv[j] = t ? ov : bv[j]; bi[j] = t ? oi : bi[j]; \
    }
    DSTEP(0x121) DSTEP(0x122) DSTEP(0x124) DSTEP(0x128)
    #undef DSTEP
    #pragma unroll
    for (int j=0;j<4;j++){
      selm[j] |= (((bi[j]&15)==lr) ? (1u<<(bi[j]>>4)) : 0u);
      #pragma unroll
      for (int nf=0;nf<8;nf++)
        sm[nf][j] = (bi[j] == nf*16+lr) ? -3e38f : sm[nf][j];
    }
  }

  // combined gated prob row -> LDS (bf16)
  float gcv[4], gsv[4];
  #pragma unroll
  for (int j=0;j<4;j++){
    int qq = q0 + w*16 + 4*g + j;
    gcv[j] = gc[(size_t)b*Tlen + qq];
    gsv[j] = gs[(size_t)b*Tlen + qq];
  }
  #pragma unroll
  for (int nf=0;nf<8;nf++){
    int n = nf*16+lr;
    #pragma unroll
    for (int j=0;j<4;j++){
      float pcm = e[nf][j]*rzc[j];
      float ps  = (al[nf] && ((selm[j]>>nf)&1u)) ? e[nf][j]*rzs[j] : 0.f;
      Pc[(w*16+4*g+j)*136 + n] = f2bf(gcv[j]*pcm + gsv[j]*ps);
    }
  }
  __syncthreads();

  bf16x8 pa[4];
  #pragma unroll
  for (int kc=0;kc<4;kc++) pa[kc] = *(const bf16x8*)(&Pc[(w*16+lr)*136 + kc*32 + g*8]);
  f32x4 po[16];
  #pragma unroll
  for (int i=0;i<16;i++) po[i]=f32x4{0.f,0.f,0.f,0.f};
  const unsigned short* cvb = cvt + (size_t)b*Dd*NBc;
  #pragma unroll
  for (int nf2=0;nf2<16;nf2++){
    #pragma unroll
    for (int kc=0;kc<4;kc++){
      bf16x8 vb = *(const bf16x8*)(cvb + (size_t)(nf2*16+lr)*NBc + kc*32 + g*8);
      po[nf2] = mfma16(pa[kc], vb, po[nf2]);
    }
  }
  #pragma unroll
  for (int nf2=0;nf2<16;nf2++){
    #pragma unroll
    for (int j=0;j<4;j++){
      out[((size_t)b*Tlen + q0 + w*16 + 4*g + j)*Dd + nf2*16 + lr] = po[nf2][j];
    }
  }
}

// ---------------- SWA flash attention: 128-q tiles, 8 waves, 32x32 MFMA, swapped ops, no-max softmax
template<bool KPRE>
__global__ __launch_bounds__(512,2) void k_swa2(const float* __restrict__ Q, const float* __restrict__ Kf,
    const unsigned short* __restrict__ Kswz, const unsigned short* __restrict__ Vswz,
    const float* __restrict__ gw, float* __restrict__ out, int nt){
  __shared__ __align__(16) unsigned short Ks[2][16384];
  __shared__ __align__(16) unsigned short Vs[2][16384];
  __shared__ __align__(16) unsigned short Ps[8192];
  __shared__ float Lp[2][128];

  int wg = blockIdx.x;
  int lin = ((nt & 7) == 0) ? ((wg & 7)*(nt >> 3) + (wg >> 3)) : wg;
  int b = lin >> 6, tile = lin & 63;
  int q0 = tile*128;
  int t = threadIdx.x, w = t>>6, l = t&63;
  int lq = l & 31, h = l >> 5;
  int qf = w & 3, kh = w >> 2;

  // Q as B-fragments (col=q=lane&31, k-rows=d=(lane>>5)*8+j), resident
  bf16x8 qb[16];
  {
    const float* qrow = Q + ((size_t)b*Tlen + q0 + qf*32 + lq)*Dd + h*8;
    #pragma unroll
    for (int kst=0;kst<16;kst++){
      f32x4 a0 = *(const f32x4*)(qrow + kst*16);
      f32x4 a1 = *(const f32x4*)(qrow + kst*16 + 4);
      qb[kst] = pack8(a0, a1);
    }
  }

  f32x16 po[4];
  #pragma unroll
  for (int i=0;i<4;i++) po[i] = (f32x16)(0.f);
  float lacc = 0.f;

  int jb0 = tile*2 - 8; if (jb0 < 0) jb0 = 0;
  const int jbmax = tile*2 + 1;
  const size_t bofK = (size_t)b*NBc*16384;

  auto stage = [&](int buf, int jb){
    const unsigned short* ks = Kswz + bofK + (size_t)jb*16384 + t*8;
    const unsigned short* vs = Vswz + bofK + (size_t)jb*16384 + t*8;
    #pragma unroll
    for (int i=0;i<4;i++) GLL16(ks + i*4096, &Ks[buf][t*8 + i*4096]);
    #pragma unroll
    for (int i=0;i<4;i++) GLL16(vs + i*4096, &Vs[buf][t*8 + i*4096]);
  };

  int cur = 0;
  if constexpr (KPRE) stage(0, jb0);

  for (int jb = jb0; jb <= jbmax; ++jb){
    if constexpr (KPRE){
      bar();                                  // prev step fully consumed
      if (jb < jbmax){
        stage(cur^1, jb+1);                   // prefetch next block (async)
        asm volatile("s_waitcnt vmcnt(8)" ::: "memory");  // current block's 8 done
      } else {
        asm volatile("s_waitcnt vmcnt(0)" ::: "memory");
      }
      bar();                                  // staged data visible
    } else {
      bar();
      {
        const float* kb = Kf + ((size_t)b*Tlen + (size_t)jb*64)*Dd;
        #pragma unroll
        for (int i=0;i<4;i++){
          int id = i*512 + t, r = id>>5, c = id&31;
          f32x4 a0 = *(const f32x4*)(kb + (size_t)r*Dd + c*8);
          f32x4 a1 = *(const f32x4*)(kb + (size_t)r*Dd + c*8 + 4);
          *(bf16x8*)(&Ks[0][r*256 + ((c ^ (r&7))*8)]) = pack8(a0,a1);
        }
        const unsigned short* vs = Vswz + bofK + (size_t)jb*16384 + t*8;
        #pragma unroll
        for (int i=0;i<4;i++) GLL16(vs + i*4096, &Vs[0][t*8 + i*4096]);
      }
      asm volatile("s_waitcnt vmcnt(0) lgkmcnt(0)" ::: "memory");
      bar();
    }

    // S^T = K * Q^T  (wave: keys kh*32..+31  x  q qf*32..+31)
    f32x16 s = (f32x16)(0.f);
    {
      int rowK = kh*32 + lq;
      const unsigned short* Krow = &Ks[cur][rowK*256];
      int xk = rowK & 7;
      #pragma unroll
      for (int kst=0;kst<16;kst++){
        bf16x8 kf = *(const bf16x8*)(Krow + (((kst*2 + h) ^ xk)*8));
        s = mfma32(kf, qb[kst], s);
      }
    }
    // mask + exp (no-max-subtraction: scores ~N(0,1), fp32-safe) + partial row-sum
    {
      float pv[16];
      int kbase = jb*64 + kh*32 + 4*h;
      int qg = q0 + qf*32 + lq;
      #pragma unroll
      for (int r=0;r<16;r++){
        int k = kbase + (r&3) + 8*(r>>2);
        float e = (k <= qg && k >= qg-511) ? __expf(s[r]*0.0625f) : 0.f;
        lacc += e; pv[r] = e;
      }
      char* Pr = (char*)&Ps[(qf*32+lq)*64];
      int xq = lq & 7;
      #pragma unroll
      for (int rq=0;rq<4;rq++){
        uint2 val;
        val.x = pkbf(pv[4*rq+0], pv[4*rq+1]);
        val.y = pkbf(pv[4*rq+2], pv[4*rq+3]);
        *(uint2*)(Pr + (((kh*4+rq) ^ xq)*16) + h*8) = val;
      }
    }
    asm volatile("s_waitcnt lgkmcnt(0)" ::: "memory");
    bar();                                    // P visible to all waves
    // O^T += V^T * P^T   (wave owns d-slice w*32..+31, all 128 q)
    {
      const char* Vrow = (const char*)&Vs[cur][(w*32+lq)*64];
      int xv = lq & 7;
      #pragma unroll
      for (int k2=0;k2<4;k2++){
        bf16x8 vf = *(const bf16x8*)(Vrow + (((k2*2+h) ^ xv)*16));
        #pragma unroll
        for (int q2=0;q2<4;q2++){
          const char* Pq = (const char*)&Ps[(q2*32+lq)*64];
          bf16x8 pf = *(const bf16x8*)(Pq + (((k2*2+h) ^ xv)*16));
          po[q2] = mfma32(vf, pf, po[q2]);
        }
      }
    }
    if constexpr (KPRE) cur ^= 1;
  }

  // combine row-sums: xor32 merges h-halves; LDS merges kh-halves
  lacc += __shfl_xor(lacc, 32);
  if (l < 32) Lp[kh][qf*32 + l] = lacc;
  __syncthreads();
  #pragma unroll
  for (int q2=0;q2<4;q2++){
    int q = q0 + q2*32 + lq;
    float scale = gw[(size_t)b*Tlen + q] / (Lp[0][q2*32+lq] + Lp[1][q2*32+lq]);
    #pragma unroll
    for (int rq=0;rq<4;rq++){
      float* op = out + ((size_t)b*Tlen + q)*Dd + w*32 + rq*8 + h*4;
      f32x4 prev = *(f32x4*)op;
      f32x4 add;
      #pragma unroll
      for (int ii=0;ii<4;ii++) add[ii] = prev[ii] + po[q2][4*rq+ii]*scale;
      *(f32x4*)op = add;
    }
  }
}

extern "C" void kernel_launch(void* const* d_in, const int* in_sizes, int n_in,
                              void* d_out, int out_size, void* d_ws, size_t ws_size,
                              hipStream_t stream) {
  const float* Q  = (const float*)d_in[0];
  const float* K  = (const float*)d_in[1];
  const float* V  = (const float*)d_in[2];
  const float* gc = (const float*)d_in[3];
  const float* gs = (const float*)d_in[4];
  const float* gwp= (const float*)d_in[5];
  float* out = (float*)d_out;
  int B = in_sizes[0] / (Tlen*Dd);

  unsigned short* ck  = (unsigned short*)d_ws;                    // [B][128][256] bf16
  unsigned short* cvt = ck  + (size_t)B*NBc*Dd;                   // [B][256][128] bf16
  unsigned short* Vsw = cvt + (size_t)B*Dd*NBc;                   // [B][128 blk][256 d][64 k] bf16 swizzled
  unsigned short* Ksw = Vsw + (size_t)B*Tlen*Dd;                  // [B][128 blk][64 r][256 d] bf16 swizzled

  size_t need_full = ((size_t)B*((size_t)NBc*Dd + (size_t)Dd*NBc + 2*(size_t)Tlen*Dd))*2;
  bool kpre = ws_size >= need_full;
  int nt = B*64;

  k_prep   <<<dim3(B*128), dim3(256), 0, stream>>>(K, V, ck, cvt, Vsw, Ksw, kpre?1:0);
  k_compsel<<<dim3(B*128), dim3(256), 0, stream>>>(Q, ck, cvt, gc, gs, out);
  if (kpre) k_swa2<true ><<<dim3(nt), dim3(512), 0, stream>>>(Q, K, Ksw, Vsw, gwp, out, nt);
  else      k_swa2<false><<<dim3(nt), dim3(512), 0, stream>>>(Q, K, Ksw, Vsw, gwp, out, nt);
}

// Round 8
// 131.477 us; speedup vs baseline: 1.0416x; 1.0416x over previous
//
#include <hip/hip_runtime.h>
#include <hip/hip_bf16.h>

#define Tlen 8192
#define Dd 256
#define NBc 128

typedef __attribute__((ext_vector_type(4))) float f32x4;
typedef __attribute__((ext_vector_type(16))) float f32x16;
typedef __attribute__((ext_vector_type(8))) short bf16x8;

__device__ __forceinline__ unsigned short f2bf(float f){
  unsigned u = __builtin_bit_cast(unsigned, f);
  u += 0x7fffu + ((u >> 16) & 1u);
  return (unsigned short)(u >> 16);
}
__device__ __forceinline__ f32x4 mfma16(bf16x8 a, bf16x8 b, f32x4 c){
  return __builtin_amdgcn_mfma_f32_16x16x32_bf16(a, b, c, 0, 0, 0);
}
__device__ __forceinline__ f32x16 mfma32(bf16x8 a, bf16x8 b, f32x16 c){
  return __builtin_amdgcn_mfma_f32_32x32x16_bf16(a, b, c, 0, 0, 0);
}
__device__ __forceinline__ unsigned pkbf(float a, float b){
  unsigned r; asm("v_cvt_pk_bf16_f32 %0, %1, %2" : "=v"(r) : "v"(a), "v"(b)); return r;
}
__device__ __forceinline__ void bar(){
  asm volatile("" ::: "memory");
  __builtin_amdgcn_s_barrier();
  asm volatile("" ::: "memory");
}
__device__ __forceinline__ bf16x8 pack8(f32x4 a0, f32x4 a1){
  bf16x8 o;
  o[0]=(short)f2bf(a0[0]); o[1]=(short)f2bf(a0[1]); o[2]=(short)f2bf(a0[2]); o[3]=(short)f2bf(a0[3]);
  o[4]=(short)f2bf(a1[0]); o[5]=(short)f2bf(a1[1]); o[6]=(short)f2bf(a1[2]); o[7]=(short)f2bf(a1[3]);
  return o;
}
#define GLL16(g, l) __builtin_amdgcn_global_load_lds( \
    (const __attribute__((address_space(1))) unsigned int*)(const void*)(g), \
    (__attribute__((address_space(3))) unsigned int*)(void*)(l), 16, 0, 0)

// DPP 16-lane row rotations (lane groups of 16 == DPP rows)
template<int C>
__device__ __forceinline__ int dppi(int x){
  return __builtin_amdgcn_update_dpp(x, x, C, 0xF, 0xF, false);
}
template<int C>
__device__ __forceinline__ float dppf(float x){
  return __builtin_bit_cast(float, dppi<C>(__builtin_bit_cast(int, x)));
}
__device__ __forceinline__ float dpp_sum16(float x){
  x += dppf<0x121>(x); x += dppf<0x122>(x); x += dppf<0x124>(x); x += dppf<0x128>(x);
  return x;
}

// Load A-fragment (row = lane&15) for 16x16x32: 8 consecutive k at (l>>4)*8
__device__ __forceinline__ bf16x8 load_qfrag(const float* qrow, int kc, int g){
  f32x4 v0 = *(const f32x4*)(qrow + kc*32 + g*8);
  f32x4 v1 = *(const f32x4*)(qrow + kc*32 + g*8 + 4);
  return pack8(v0, v1);
}

// ---------------- Prep: means (ck, cvt) + swizzled bf16 K blocks + swizzled bf16 V^T blocks
__global__ __launch_bounds__(256) void k_prep(const float* __restrict__ K, const float* __restrict__ V,
    unsigned short* __restrict__ ck, unsigned short* __restrict__ cvt,
    unsigned short* __restrict__ Vswz, unsigned short* __restrict__ Kswz, int do_k){
  __shared__ unsigned short Lt[64][72];
  int b = blockIdx.x >> 7, blk = blockIdx.x & 127;
  int t = threadIdx.x;
  const float* Kb = K + ((size_t)b*Tlen + (size_t)blk*64)*Dd;
  const float* Vb = V + ((size_t)b*Tlen + (size_t)blk*64)*Dd;
  {
    float sk=0.f, sv=0.f;
    #pragma unroll 8
    for (int i=0;i<64;i++){ sk += Kb[(size_t)i*Dd + t]; sv += Vb[(size_t)i*Dd + t]; }
    ck[((size_t)b*NBc + blk)*Dd + t] = f2bf(sk*(1.f/64.f));
    cvt[((size_t)b*Dd + t)*NBc + blk] = f2bf(sv*(1.f/64.f));
  }
  if (do_k){
    unsigned short* kd = Kswz + ((size_t)(b*NBc + blk))*16384;
    #pragma unroll
    for (int i=0;i<8;i++){
      int id = i*256 + t, r = id>>5, c = id&31;
      f32x4 a0 = *(const f32x4*)(Kb + (size_t)r*Dd + c*8);
      f32x4 a1 = *(const f32x4*)(Kb + (size_t)r*Dd + c*8 + 4);
      *(bf16x8*)(kd + r*256 + ((c ^ (r&7))*8)) = pack8(a0,a1);
    }
  }
  unsigned short* vd = Vswz + ((size_t)(b*NBc + blk))*16384;
  for (int dt=0; dt<4; ++dt){
    __syncthreads();
    #pragma unroll
    for (int it=0; it<4; ++it){
      int idx = it*256 + t, r = idx>>4, c4 = idx&15;
      f32x4 v = *(const f32x4*)(Vb + (size_t)r*Dd + dt*64 + c4*4);
      #pragma unroll
      for (int ii=0;ii<4;ii++) Lt[c4*4+ii][r] = f2bf(v[ii]);
    }
    __syncthreads();
    int dd = t>>2, ch = t&3, d = dt*64 + dd;
    unsigned short tmp[16];
    #pragma unroll
    for (int u=0;u<16;u++) tmp[u] = Lt[dd][ch*16+u];
    *(bf16x8*)(vd + d*64 + (((ch*2  ) ^ (d&7))*8)) = *(bf16x8*)(tmp);
    *(bf16x8*)(vd + d*64 + (((ch*2+1) ^ (d&7))*8)) = *(bf16x8*)(tmp+8);
  }
}

// ---------------- comp + selective: proven DPP extraction + register-staged prefetch pipeline
__global__ __launch_bounds__(256,2) void k_compsel(const float* __restrict__ Q,
    const unsigned short* __restrict__ ck, const unsigned short* __restrict__ cvt,
    const float* __restrict__ gc, const float* __restrict__ gs, float* __restrict__ out){
  __shared__ unsigned short Pc[64*136];
  int b = blockIdx.x >> 7, tile = blockIdx.x & 127;
  int q0 = tile*64;
  int w = threadIdx.x >> 6, l = threadIdx.x & 63, g = l >> 4, lr = l & 15;

  // gates issued first (independent scalar loads)
  float gcv[4], gsv[4];
  #pragma unroll
  for (int j=0;j<4;j++){
    int qq = q0 + w*16 + 4*g + j;
    gcv[j] = gc[(size_t)b*Tlen + qq];
    gsv[j] = gs[(size_t)b*Tlen + qq];
  }

  bf16x8 qa[8];
  const float* qrow = Q + ((size_t)b*Tlen + q0 + w*16 + lr)*Dd;
  #pragma unroll
  for (int kc=0;kc<8;kc++) qa[kc] = load_qfrag(qrow, kc, g);

  // QK: 2-deep ping-pong prefetch of B-fragments (8 loads/chunk, 8-16 in flight)
  const unsigned short* ckb = ck + (size_t)b*NBc*Dd;
  bf16x8 pb[2][8];
  #pragma unroll
  for (int kc=0;kc<8;kc++)
    pb[0][kc] = *(const bf16x8*)(ckb + (size_t)lr*Dd + kc*32 + g*8);
  f32x4 acc[8];
  #pragma unroll
  for (int nf=0;nf<8;nf++) acc[nf] = f32x4{0.f,0.f,0.f,0.f};
  #pragma unroll
  for (int nf=0;nf<8;nf++){
    if (nf < 7){
      #pragma unroll
      for (int kc=0;kc<8;kc++)
        pb[(nf+1)&1][kc] = *(const bf16x8*)(ckb + (size_t)((nf+1)*16+lr)*Dd + kc*32 + g*8);
    }
    #pragma unroll
    for (int kc=0;kc<8;kc++) acc[nf] = mfma16(qa[kc], pb[nf&1][kc], acc[nf]);
  }
  #pragma unroll
  for (int nf=0;nf<8;nf++) acc[nf] *= 0.0625f;

  // exp once (scores ~N(0,0.125): no max subtraction needed in fp32)
  bool al[8];
  #pragma unroll
  for (int nf=0;nf<8;nf++) al[nf] = (nf*16+lr) <= tile;
  f32x4 e[8];
  #pragma unroll
  for (int nf=0;nf<8;nf++){
    #pragma unroll
    for (int j=0;j<4;j++) e[nf][j] = __expf(acc[nf][j]);
  }
  // row sums via DPP (zc: all cols; zs: causal-allowed cols)
  f32x4 zc4 = f32x4{0.f,0.f,0.f,0.f}, zs4 = f32x4{0.f,0.f,0.f,0.f};
  #pragma unroll
  for (int nf=0;nf<8;nf++){
    zc4 += e[nf];
    #pragma unroll
    for (int j=0;j<4;j++) zs4[j] += al[nf] ? e[nf][j] : 0.f;
  }
  float rzc[4], rzs[4];
  #pragma unroll
  for (int j=0;j<4;j++){
    rzc[j] = 1.f / dpp_sum16(zc4[j]);
    rzs[j] = 1.f / dpp_sum16(zs4[j]);
  }

  // issue first PV prefetch chunk (nf2=0..3, 16 loads) BEFORE extraction — latency hidden under it
  const unsigned short* cvb = cvt + (size_t)b*Dd*NBc;
  bf16x8 vb[4][4];
  #pragma unroll
  for (int c2=0;c2<4;c2++){
    #pragma unroll
    for (int kc=0;kc<4;kc++)
      vb[c2][kc] = *(const bf16x8*)(cvb + (size_t)(c2*16+lr)*NBc + kc*32 + g*8);
  }

  // top-16 extraction: 16 iterations, DPP argmax over the 16-lane row, 4 rows in flight
  f32x4 sm[8];
  #pragma unroll
  for (int nf=0;nf<8;nf++){
    #pragma unroll
    for (int j=0;j<4;j++) sm[nf][j] = al[nf] ? acc[nf][j] : -3e38f;
  }
  unsigned selm[4]={0,0,0,0};
  #pragma unroll 1
  for (int it=0; it<16; ++it){
    float bv[4]; int bi[4];
    #pragma unroll
    for (int j=0;j<4;j++){
      float v = sm[0][j]; int n = lr;
      #pragma unroll
      for (int nf=1;nf<8;nf++){
        bool t = sm[nf][j] > v;
        v = t ? sm[nf][j] : v;
        n = t ? nf*16+lr : n;
      }
      bv[j]=v; bi[j]=n;
    }
    #define DSTEP(CTRL) \
    _Pragma("unroll") \
    for (int j=0;j<4;j++){ \
      float ov = dppf<CTRL>(bv[j]); int oi = dppi<CTRL>(bi[j]); \
      bool t = (ov>bv[j]) || (ov==bv[j] && oi<bi[j]); \
      bv[j] = t ? ov : bv[j]; bi[j] = t ? oi : bi[j]; \
    }
    DSTEP(0x121) DSTEP(0x122) DSTEP(0x124) DSTEP(0x128)
    #undef DSTEP
    #pragma unroll
    for (int j=0;j<4;j++){
      selm[j] |= (((bi[j]&15)==lr) ? (1u<<(bi[j]>>4)) : 0u);
      #pragma unroll
      for (int nf=0;nf<8;nf++)
        sm[nf][j] = (bi[j] == nf*16+lr) ? -3e38f : sm[nf][j];
    }
  }

  // combined gated prob row -> LDS (bf16); waves touch only their own 16 rows (no barrier needed)
  #pragma unroll
  for (int nf=0;nf<8;nf++){
    int n = nf*16+lr;
    #pragma unroll
    for (int j=0;j<4;j++){
      float pcm = e[nf][j]*rzc[j];
      float ps  = (al[nf] && ((selm[j]>>nf)&1u)) ? e[nf][j]*rzs[j] : 0.f;
      Pc[(w*16+4*g+j)*136 + n] = f2bf(gcv[j]*pcm + gsv[j]*ps);
    }
  }
  asm volatile("" ::: "memory");   // same-wave LDS is in-order; keep compiler from reordering

  bf16x8 pa[4];
  #pragma unroll
  for (int kc=0;kc<4;kc++) pa[kc] = *(const bf16x8*)(&Pc[(w*16+lr)*136 + kc*32 + g*8]);
  f32x4 po[16];
  #pragma unroll
  for (int i=0;i<16;i++) po[i]=f32x4{0.f,0.f,0.f,0.f};
  // PV with rolling 4-slot prefetch (12-16 loads in flight)
  #pragma unroll
  for (int nf2=0;nf2<16;nf2++){
    int slot = nf2 & 3;
    #pragma unroll
    for (int kc=0;kc<4;kc++) po[nf2] = mfma16(pa[kc], vb[slot][kc], po[nf2]);
    if (nf2 < 12){
      #pragma unroll
      for (int kc=0;kc<4;kc++)
        vb[slot][kc] = *(const bf16x8*)(cvb + (size_t)((nf2+4)*16+lr)*NBc + kc*32 + g*8);
    }
  }
  #pragma unroll
  for (int nf2=0;nf2<16;nf2++){
    #pragma unroll
    for (int j=0;j<4;j++){
      out[((size_t)b*Tlen + q0 + w*16 + 4*g + j)*Dd + nf2*16 + lr] = po[nf2][j];
    }
  }
}

// ---------------- SWA flash attention: 128-q tiles, 8 waves, 32x32 MFMA, swapped ops, no-max softmax
template<bool KPRE>
__global__ __launch_bounds__(512,2) void k_swa2(const float* __restrict__ Q, const float* __restrict__ Kf,
    const unsigned short* __restrict__ Kswz, const unsigned short* __restrict__ Vswz,
    const float* __restrict__ gw, float* __restrict__ out, int nt){
  __shared__ __align__(16) unsigned short Ks[2][16384];
  __shared__ __align__(16) unsigned short Vs[2][16384];
  __shared__ __align__(16) unsigned short Ps[8192];
  __shared__ float Lp[2][128];

  int wg = blockIdx.x;
  int lin = ((nt & 7) == 0) ? ((wg & 7)*(nt >> 3) + (wg >> 3)) : wg;
  int b = lin >> 6, tile = lin & 63;
  int q0 = tile*128;
  int t = threadIdx.x, w = t>>6, l = t&63;
  int lq = l & 31, h = l >> 5;
  int qf = w & 3, kh = w >> 2;

  // Q as B-fragments (col=q=lane&31, k-rows=d=(lane>>5)*8+j), resident
  bf16x8 qb[16];
  {
    const float* qrow = Q + ((size_t)b*Tlen + q0 + qf*32 + lq)*Dd + h*8;
    #pragma unroll
    for (int kst=0;kst<16;kst++){
      f32x4 a0 = *(const f32x4*)(qrow + kst*16);
      f32x4 a1 = *(const f32x4*)(qrow + kst*16 + 4);
      qb[kst] = pack8(a0, a1);
    }
  }

  f32x16 po[4];
  #pragma unroll
  for (int i=0;i<4;i++) po[i] = (f32x16)(0.f);
  float lacc = 0.f;

  int jb0 = tile*2 - 8; if (jb0 < 0) jb0 = 0;
  const int jbmax = tile*2 + 1;
  const size_t bofK = (size_t)b*NBc*16384;

  auto stage = [&](int buf, int jb){
    const unsigned short* ks = Kswz + bofK + (size_t)jb*16384 + t*8;
    const unsigned short* vs = Vswz + bofK + (size_t)jb*16384 + t*8;
    #pragma unroll
    for (int i=0;i<4;i++) GLL16(ks + i*4096, &Ks[buf][t*8 + i*4096]);
    #pragma unroll
    for (int i=0;i<4;i++) GLL16(vs + i*4096, &Vs[buf][t*8 + i*4096]);
  };

  int cur = 0;
  if constexpr (KPRE) stage(0, jb0);

  for (int jb = jb0; jb <= jbmax; ++jb){
    if constexpr (KPRE){
      bar();                                  // prev step fully consumed
      if (jb < jbmax){
        stage(cur^1, jb+1);                   // prefetch next block (async)
        asm volatile("s_waitcnt vmcnt(8)" ::: "memory");  // current block's 8 done
      } else {
        asm volatile("s_waitcnt vmcnt(0)" ::: "memory");
      }
      bar();                                  // staged data visible
    } else {
      bar();
      {
        const float* kb = Kf + ((size_t)b*Tlen + (size_t)jb*64)*Dd;
        #pragma unroll
        for (int i=0;i<4;i++){
          int id = i*512 + t, r = id>>5, c = id&31;
          f32x4 a0 = *(const f32x4*)(kb + (size_t)r*Dd + c*8);
          f32x4 a1 = *(const f32x4*)(kb + (size_t)r*Dd + c*8 + 4);
          *(bf16x8*)(&Ks[0][r*256 + ((c ^ (r&7))*8)]) = pack8(a0,a1);
        }
        const unsigned short* vs = Vswz + bofK + (size_t)jb*16384 + t*8;
        #pragma unroll
        for (int i=0;i<4;i++) GLL16(vs + i*4096, &Vs[0][t*8 + i*4096]);
      }
      asm volatile("s_waitcnt vmcnt(0) lgkmcnt(0)" ::: "memory");
      bar();
    }

    // S^T = K * Q^T  (wave: keys kh*32..+31  x  q qf*32..+31)
    f32x16 s = (f32x16)(0.f);
    {
      int rowK = kh*32 + lq;
      const unsigned short* Krow = &Ks[cur][rowK*256];
      int xk = rowK & 7;
      #pragma unroll
      for (int kst=0;kst<16;kst++){
        bf16x8 kf = *(const bf16x8*)(Krow + (((kst*2 + h) ^ xk)*8));
        s = mfma32(kf, qb[kst], s);
      }
    }
    // mask + exp (no-max-subtraction: scores ~N(0,1), fp32-safe) + partial row-sum
    {
      float pv[16];
      int kbase = jb*64 + kh*32 + 4*h;
      int qg = q0 + qf*32 + lq;
      #pragma unroll
      for (int r=0;r<16;r++){
        int k = kbase + (r&3) + 8*(r>>2);
        float e = (k <= qg && k >= qg-511) ? __expf(s[r]*0.0625f) : 0.f;
        lacc += e; pv[r] = e;
      }
      char* Pr = (char*)&Ps[(qf*32+lq)*64];
      int xq = lq & 7;
      #pragma unroll
      for (int rq=0;rq<4;rq++){
        uint2 val;
        val.x = pkbf(pv[4*rq+0], pv[4*rq+1]);
        val.y = pkbf(pv[4*rq+2], pv[4*rq+3]);
        *(uint2*)(Pr + (((kh*4+rq) ^ xq)*16) + h*8) = val;
      }
    }
    asm volatile("s_waitcnt lgkmcnt(0)" ::: "memory");
    bar();                                    // P visible to all waves
    // O^T += V^T * P^T   (wave owns d-slice w*32..+31, all 128 q)
    {
      const char* Vrow = (const char*)&Vs[cur][(w*32+lq)*64];
      int xv = lq & 7;
      #pragma unroll
      for (int k2=0;k2<4;k2++){
        bf16x8 vf = *(const bf16x8*)(Vrow + (((k2*2+h) ^ xv)*16));
        #pragma unroll
        for (int q2=0;q2<4;q2++){
          const char* Pq = (const char*)&Ps[(q2*32+lq)*64];
          bf16x8 pf = *(const bf16x8*)(Pq + (((k2*2+h) ^ xv)*16));
          po[q2] = mfma32(vf, pf, po[q2]);
        }
      }
    }
    if constexpr (KPRE) cur ^= 1;
  }

  // combine row-sums: xor32 merges h-halves; LDS merges kh-halves
  lacc += __shfl_xor(lacc, 32);
  if (l < 32) Lp[kh][qf*32 + l] = lacc;
  __syncthreads();
  #pragma unroll
  for (int q2=0;q2<4;q2++){
    int q = q0 + q2*32 + lq;
    float scale = gw[(size_t)b*Tlen + q] / (Lp[0][q2*32+lq] + Lp[1][q2*32+lq]);
    #pragma unroll
    for (int rq=0;rq<4;rq++){
      float* op = out + ((size_t)b*Tlen + q)*Dd + w*32 + rq*8 + h*4;
      f32x4 prev = *(f32x4*)op;
      f32x4 add;
      #pragma unroll
      for (int ii=0;ii<4;ii++) add[ii] = prev[ii] + po[q2][4*rq+ii]*scale;
      *(f32x4*)op = add;
    }
  }
}

extern "C" void kernel_launch(void* const* d_in, const int* in_sizes, int n_in,
                              void* d_out, int out_size, void* d_ws, size_t ws_size,
                              hipStream_t stream) {
  const float* Q  = (const float*)d_in[0];
  const float* K  = (const float*)d_in[1];
  const float* V  = (const float*)d_in[2];
  const float* gc = (const float*)d_in[3];
  const float* gs = (const float*)d_in[4];
  const float* gwp= (const float*)d_in[5];
  float* out = (float*)d_out;
  int B = in_sizes[0] / (Tlen*Dd);

  unsigned short* ck  = (unsigned short*)d_ws;                    // [B][128][256] bf16
  unsigned short* cvt = ck  + (size_t)B*NBc*Dd;                   // [B][256][128] bf16
  unsigned short* Vsw = cvt + (size_t)B*Dd*NBc;                   // [B][128 blk][256 d][64 k] bf16 swizzled
  unsigned short* Ksw = Vsw + (size_t)B*Tlen*Dd;                  // [B][128 blk][64 r][256 d] bf16 swizzled

  size_t need_full = ((size_t)B*((size_t)NBc*Dd + (size_t)Dd*NBc + 2*(size_t)Tlen*Dd))*2;
  bool kpre = ws_size >= need_full;
  int nt = B*64;

  k_prep   <<<dim3(B*128), dim3(256), 0, stream>>>(K, V, ck, cvt, Vsw, Ksw, kpre?1:0);
  k_compsel<<<dim3(B*128), dim3(256), 0, stream>>>(Q, ck, cvt, gc, gs, out);
  if (kpre) k_swa2<true ><<<dim3(nt), dim3(512), 0, stream>>>(Q, K, Ksw, Vsw, gwp, out, nt);
  else      k_swa2<false><<<dim3(nt), dim3(512), 0, stream>>>(Q, K, Ksw, Vsw, gwp, out, nt);
}